// Round 7
// baseline (2078.932 us; speedup 1.0000x reference)
//
#include <hip/hip_runtime.h>
#include <math.h>

// ---------------------------------------------------------------------------
// Encoder on MI355X.
// NHWC fp16 activations; ALL convs as tap-wise implicit GEMM on
// mfma_f32_16x16x32_f16 (fp32 accum). InstanceNorm stats are computed in each
// conv's epilogue (shfl-reduce + atomicAdd into per-layer Ssum slots); the
// consumer computes mean/rstd inline from Ssum during staging (norm+ReLU
// fused). No standalone stats kernels.
// ---------------------------------------------------------------------------

typedef _Float16 half_t;
typedef _Float16 halfx8 __attribute__((ext_vector_type(8)));
typedef _Float16 halfx4 __attribute__((ext_vector_type(4)));
typedef float floatx4 __attribute__((ext_vector_type(4)));

// ---------------- weight transform: -> fp16 [tap][Cout][Cin] ----------------
// mode 0: src OIHW [Cout][Cin][3][3]; mode 1: src IOHW [Cin][Cout][3][3]
__global__ __launch_bounds__(256) void transform_w(
    const float* __restrict__ src, half_t* __restrict__ dst,
    int Cin, int Cout, int mode)
{
  int idx = blockIdx.x * 256 + threadIdx.x;
  int total = Cin * Cout * 9;
  if (idx >= total) return;
  int tap = idx % 9, t2 = idx / 9;
  int co, ci;
  if (mode == 0) { ci = t2 % Cin; co = t2 / Cin; }
  else           { co = t2 % Cout; ci = t2 / Cout; }
  dst[((size_t)tap * Cout + co) * Cin + ci] = (half_t)src[idx];
}

// final-conv weights: src [3][64][7][7] -> dst [tap49][co16(pad0)][ci64]
__global__ __launch_bounds__(256) void transform_wf(
    const float* __restrict__ src, half_t* __restrict__ dst)
{
  int idx = blockIdx.x * 256 + threadIdx.x;
  if (idx >= 49 * 16 * 64) return;
  int ci = idx & 63, t = idx >> 6;
  int co = t & 15, tap = t >> 4;
  float v = (co < 3) ? src[((size_t)co * 64 + ci) * 49 + tap] : 0.f;
  dst[idx] = (half_t)v;
}

// first-conv weights: src [64][3][7][7] -> dst [ky7][co64][k32], k=kx*4+ci
__global__ __launch_bounds__(256) void transform_w0(
    const float* __restrict__ src, half_t* __restrict__ dst)
{
  int idx = blockIdx.x * 256 + threadIdx.x;
  if (idx >= 7 * 64 * 32) return;
  int k = idx & 31, t = idx >> 5;
  int co = t & 63, ky = t >> 6;
  int kx = k >> 2, ci = k & 3;
  float v = (ci < 3 && kx < 7) ? src[(((size_t)co * 3 + ci) * 7 + ky) * 7 + kx] : 0.f;
  dst[idx] = (half_t)v;
}

// ---------------- conv0: reflect pad 3, 7x7, 3 -> 64, MFMA, stats-fused -----
__global__ __launch_bounds__(256) void conv0_mfma(
    const float* __restrict__ x, const half_t* __restrict__ wt,
    const float* __restrict__ bias, half_t* __restrict__ out,
    float* __restrict__ ssOut)
{
  const int H = 512, W = 512;
  __shared__ _Float16 sX[22 * 24 * 4];   // [row 22][col 24][ci 4]  (4.2 KB)
  __shared__ _Float16 sO[256 * 72];      // [pixel 256][co 64 pad 72] (36.9 KB)
  const int tile = blockIdx.x, b = blockIdx.y;
  const int tx0 = (tile & 31) << 4, ty0 = (tile >> 5) << 4;
  const int tid = threadIdx.x;
  const int wave = tid >> 6, lane = tid & 63;
  const int ln = lane & 15, g = lane >> 4;

  for (int u = tid; u < 22 * 24; u += 256) {
    int row = u / 24, col = u % 24;
    halfx4 v = {0, 0, 0, 0};
    if (col < 22) {
      int gy = ty0 + row - 3, gx = tx0 + col - 3;
      gy = gy < 0 ? -gy : (gy >= H ? 2 * H - 2 - gy : gy);
      gx = gx < 0 ? -gx : (gx >= W ? 2 * W - 2 - gx : gx);
      size_t p = (size_t)b * 3 * H * W + (size_t)gy * W + gx;
      v[0] = (_Float16)x[p];
      v[1] = (_Float16)x[p + H * W];
      v[2] = (_Float16)x[p + 2 * H * W];
    }
    *(halfx4*)(&sX[u * 4]) = v;
  }
  __syncthreads();

  floatx4 acc[4][4];
#pragma unroll
  for (int r = 0; r < 4; ++r)
#pragma unroll
    for (int n = 0; n < 4; ++n) acc[r][n] = floatx4{0.f, 0.f, 0.f, 0.f};

#pragma unroll
  for (int ky = 0; ky < 7; ++ky) {
    halfx8 wb[4];
#pragma unroll
    for (int nt = 0; nt < 4; ++nt)
      wb[nt] = *(const halfx8*)(wt + ((size_t)ky * 64 + nt * 16 + ln) * 32 + g * 8);
#pragma unroll
    for (int rr = 0; rr < 4; ++rr) {
      int y = wave * 4 + rr;
      halfx8 a = *(const halfx8*)(&sX[((y + ky) * 24 + ln + 2 * g) * 4]);
#pragma unroll
      for (int nt = 0; nt < 4; ++nt)
        acc[rr][nt] = __builtin_amdgcn_mfma_f32_16x16x32_f16(a, wb[nt], acc[rr][nt], 0, 0, 0);
    }
  }

  // epilogue: bias, stats, transpose via LDS, vectorized NHWC store
#pragma unroll
  for (int nt = 0; nt < 4; ++nt) {
    float bs = bias[nt * 16 + ln];
    float s = 0.f, s2 = 0.f;
#pragma unroll
    for (int rr = 0; rr < 4; ++rr)
#pragma unroll
      for (int i = 0; i < 4; ++i) {
        int p = (wave * 4 + rr) * 16 + g * 4 + i;
        float v = acc[rr][nt][i] + bs;
        s += v; s2 += v * v;
        sO[p * 72 + nt * 16 + ln] = (half_t)v;
      }
    s += __shfl_xor(s, 16); s += __shfl_xor(s, 32);
    s2 += __shfl_xor(s2, 16); s2 += __shfl_xor(s2, 32);
    if (g == 0) {
      atomicAdd(&ssOut[(size_t)(b * 64 + nt * 16 + ln) * 2], s);
      atomicAdd(&ssOut[(size_t)(b * 64 + nt * 16 + ln) * 2 + 1], s2);
    }
  }
  __syncthreads();
  {
    int p = tid;
    int oy = ty0 + (p >> 4), ox = tx0 + (p & 15);
    size_t ob = ((size_t)(b * 512 + oy) * 512 + ox) * 64;
#pragma unroll
    for (int j = 0; j < 8; ++j)
      *(halfx8*)(&out[ob + j * 8]) = *(const halfx8*)(&sO[p * 72 + j * 8]);
  }
}

// ---------------- down: 3x3 s2 conv, MFMA, norm-in + stats-out fused --------
__global__ __launch_bounds__(256) void down_mfma(
    const half_t* __restrict__ in, const half_t* __restrict__ wt,
    const float* __restrict__ bias, const float* __restrict__ ssIn,
    float invN, half_t* __restrict__ out, float* __restrict__ ssOut,
    int Cin, int Cout, int IH, int IW)
{
  const int OH = IH >> 1, OW = IW >> 1;
  __shared__ _Float16 sX[9 * 33 * 40];  // [y 9][x 33][ci 32 pad 40]
  const int tid = threadIdx.x;
  const int wave = tid >> 6, lane = tid & 63;
  const int ln = lane & 15, g = lane >> 4;
  const int cog = blockIdx.x, b = blockIdx.z;
  const int ntx = OW >> 4;
  const int ox0 = (blockIdx.y % ntx) << 4, oy0 = (blockIdx.y / ntx) << 2;
  const int iy0 = 2 * oy0 - 1, ix0 = 2 * ox0 - 1;
  const int coW = cog * 128 + wave * 32;
  const int q = tid & 3;

  floatx4 acc[4][2];
#pragma unroll
  for (int r = 0; r < 4; ++r)
#pragma unroll
    for (int n = 0; n < 2; ++n) acc[r][n] = floatx4{0.f, 0.f, 0.f, 0.f};

  for (int c0 = 0; c0 < Cin; c0 += 32) {
    float mq[8], rq[8];
#pragma unroll
    for (int j = 0; j < 8; ++j) {
      int cc = c0 + q * 8 + j;
      float sA = ssIn[(size_t)(b * Cin + cc) * 2];
      float sB = ssIn[(size_t)(b * Cin + cc) * 2 + 1];
      float m = sA * invN;
      mq[j] = m;
      rq[j] = rsqrtf(sB * invN - m * m + 1e-5f);
    }
    __syncthreads();
    for (int idx = tid; idx < 9 * 33 * 4; idx += 256) {
      int p = idx >> 2;
      int y = p / 33, xx = p % 33;
      int gy = iy0 + y, gx = ix0 + xx;
      halfx8 v = {0, 0, 0, 0, 0, 0, 0, 0};
      if ((unsigned)gy < (unsigned)IH && (unsigned)gx < (unsigned)IW) {
        v = *(const halfx8*)(in + ((size_t)(b * IH + gy) * IW + gx) * Cin + c0 + q * 8);
#pragma unroll
        for (int j = 0; j < 8; ++j) {
          float f = ((float)v[j] - mq[j]) * rq[j];
          v[j] = (_Float16)(f > 0.f ? f : 0.f);
        }
      }
      *(halfx8*)(&sX[(y * 33 + xx) * 40 + q * 8]) = v;
    }
    __syncthreads();
#pragma unroll
    for (int tap = 0; tap < 9; ++tap) {
      const int ky = tap / 3, kx = tap % 3;
      halfx8 wb0 = *(const halfx8*)(wt + ((size_t)tap * Cout + coW + ln) * Cin + c0 + g * 8);
      halfx8 wb1 = *(const halfx8*)(wt + ((size_t)tap * Cout + coW + 16 + ln) * Cin + c0 + g * 8);
#pragma unroll
      for (int r = 0; r < 4; ++r) {
        halfx8 a = *(const halfx8*)(&sX[((2 * r + ky) * 33 + 2 * ln + kx) * 40 + g * 8]);
        acc[r][0] = __builtin_amdgcn_mfma_f32_16x16x32_f16(a, wb0, acc[r][0], 0, 0, 0);
        acc[r][1] = __builtin_amdgcn_mfma_f32_16x16x32_f16(a, wb1, acc[r][1], 0, 0, 0);
      }
    }
  }
#pragma unroll
  for (int nt = 0; nt < 2; ++nt) {
    int co = coW + nt * 16 + ln;
    float bs = bias[co];
    float s = 0.f, s2 = 0.f;
#pragma unroll
    for (int r = 0; r < 4; ++r)
#pragma unroll
      for (int i = 0; i < 4; ++i) {
        int oy = oy0 + r, ox = ox0 + g * 4 + i;
        float v = acc[r][nt][i] + bs;
        s += v; s2 += v * v;
        out[((size_t)(b * OH + oy) * OW + ox) * Cout + co] = (half_t)v;
      }
    s += __shfl_xor(s, 16); s += __shfl_xor(s, 32);
    s2 += __shfl_xor(s2, 16); s2 += __shfl_xor(s2, 32);
    if (g == 0) {
      atomicAdd(&ssOut[(size_t)(b * Cout + co) * 2], s);
      atomicAdd(&ssOut[(size_t)(b * Cout + co) * 2 + 1], s2);
    }
  }
}

// ---------------- up: convT k3 s2, MFMA parity classes, fused stats ---------
__global__ __launch_bounds__(256) void up_mfma(
    const half_t* __restrict__ in, const half_t* __restrict__ wt,
    const float* __restrict__ bias, const float* __restrict__ ssIn,
    float invN, half_t* __restrict__ out, float* __restrict__ ssOut,
    int Cin, int Cout, int IH, int IW)
{
  const int OH = IH << 1, OW = IW << 1;
  __shared__ _Float16 sX[5 * 17 * 40];  // [y 5][x 17][ci 32 pad 40]
  const int tid = threadIdx.x;
  const int wave = tid >> 6, lane = tid & 63;
  const int ln = lane & 15, g = lane >> 4;
  const int cog = blockIdx.x, b = blockIdx.z;
  const int ntx = OW >> 5;
  const int ox0 = (blockIdx.y % ntx) << 5, oy0 = (blockIdx.y / ntx) << 3;
  const int iyb = oy0 >> 1, ixb = ox0 >> 1;
  const int co = cog * 64 + wave * 16 + ln;
  const int q = tid & 3;

  floatx4 acc[4][4];  // [class][oyc]
#pragma unroll
  for (int c = 0; c < 4; ++c)
#pragma unroll
    for (int r = 0; r < 4; ++r) acc[c][r] = floatx4{0.f, 0.f, 0.f, 0.f};

  for (int c0 = 0; c0 < Cin; c0 += 32) {
    float mq[8], rq[8];
#pragma unroll
    for (int j = 0; j < 8; ++j) {
      int cc = c0 + q * 8 + j;
      float sA = ssIn[(size_t)(b * Cin + cc) * 2];
      float sB = ssIn[(size_t)(b * Cin + cc) * 2 + 1];
      float m = sA * invN;
      mq[j] = m;
      rq[j] = rsqrtf(sB * invN - m * m + 1e-5f);
    }
    __syncthreads();
    for (int idx = tid; idx < 5 * 17 * 4; idx += 256) {
      int p = idx >> 2;
      int y = p / 17, xx = p % 17;
      int gy = iyb + y, gx = ixb + xx;
      halfx8 v = {0, 0, 0, 0, 0, 0, 0, 0};
      if (gy < IH && gx < IW) {
        v = *(const halfx8*)(in + ((size_t)(b * IH + gy) * IW + gx) * Cin + c0 + q * 8);
#pragma unroll
        for (int j = 0; j < 8; ++j) {
          float f = ((float)v[j] - mq[j]) * rq[j];
          v[j] = (_Float16)(f > 0.f ? f : 0.f);
        }
      }
      *(halfx8*)(&sX[(y * 17 + xx) * 40 + q * 8]) = v;
    }
    __syncthreads();
#pragma unroll
    for (int tap = 0; tap < 9; ++tap) {
      const int ky = tap / 3, kx = tap % 3;
      const int cls = ((ky == 1) ? 0 : 2) + ((kx == 1) ? 0 : 1);
      const int dy = (ky == 0) ? 1 : 0;
      const int dx = (kx == 0) ? 1 : 0;
      halfx8 wb = *(const halfx8*)(wt + ((size_t)tap * Cout + co) * Cin + c0 + g * 8);
#pragma unroll
      for (int r = 0; r < 4; ++r) {
        halfx8 a = *(const halfx8*)(&sX[((r + dy) * 17 + ln + dx) * 40 + g * 8]);
        acc[cls][r] = __builtin_amdgcn_mfma_f32_16x16x32_f16(a, wb, acc[cls][r], 0, 0, 0);
      }
    }
  }
  float bs = bias[co];
  float s = 0.f, s2 = 0.f;
#pragma unroll
  for (int cls = 0; cls < 4; ++cls) {
    const int ey = cls >> 1, ex = cls & 1;
#pragma unroll
    for (int r = 0; r < 4; ++r)
#pragma unroll
      for (int i = 0; i < 4; ++i) {
        int oy = oy0 + 2 * r + ey;
        int ox = ox0 + 2 * (g * 4 + i) + ex;
        float v = acc[cls][r][i] + bs;
        s += v; s2 += v * v;
        out[((size_t)(b * OH + oy) * OW + ox) * Cout + co] = (half_t)v;
      }
  }
  s += __shfl_xor(s, 16); s += __shfl_xor(s, 32);
  s2 += __shfl_xor(s2, 16); s2 += __shfl_xor(s2, 32);
  if (g == 0) {
    atomicAdd(&ssOut[(size_t)(b * Cout + co) * 2], s);
    atomicAdd(&ssOut[(size_t)(b * Cout + co) * 2 + 1], s2);
  }
}

// ---------------- final: reflect pad 3, 7x7, 64 -> 3, MFMA + tanh -----------
// ci-chunked staging (32 at a time) -> 38.7 KB LDS -> 4 blocks/CU.
__global__ __launch_bounds__(256) void convf_mfma(
    const half_t* __restrict__ in, const half_t* __restrict__ wt,
    const float* __restrict__ bias, const float* __restrict__ ssIn,
    float invN, float* __restrict__ out)
{
  const int H = 512, W = 512;
  __shared__ _Float16 sX[484 * 40];   // [pixel 484][ci 32 pad 40] = 38.7 KB
  const int tile = blockIdx.x, b = blockIdx.y;
  const int tx0 = (tile & 31) << 4, ty0 = (tile >> 5) << 4;
  const int tid = threadIdx.x;
  const int wave = tid >> 6, lane = tid & 63;
  const int ln = lane & 15, g = lane >> 4;
  const int oc = tid & 3;

  floatx4 acc[4];
#pragma unroll
  for (int r = 0; r < 4; ++r) acc[r] = floatx4{0.f, 0.f, 0.f, 0.f};

  for (int c0 = 0; c0 < 64; c0 += 32) {
    float mq[8], rq[8];
#pragma unroll
    for (int j = 0; j < 8; ++j) {
      int cc = c0 + oc * 8 + j;
      float sA = ssIn[(size_t)(b * 64 + cc) * 2];
      float sB = ssIn[(size_t)(b * 64 + cc) * 2 + 1];
      float m = sA * invN;
      mq[j] = m;
      rq[j] = rsqrtf(sB * invN - m * m + 1e-5f);
    }
    __syncthreads();
    for (int u = tid; u < 484 * 4; u += 256) {
      int p = u >> 2;
      int iy = p / 22, ix = p % 22;
      int gy = ty0 + iy - 3, gx = tx0 + ix - 3;
      gy = gy < 0 ? -gy : (gy >= H ? 2 * H - 2 - gy : gy);
      gx = gx < 0 ? -gx : (gx >= W ? 2 * W - 2 - gx : gx);
      halfx8 v = *(const halfx8*)(in + ((size_t)(b * H + gy) * W + gx) * 64 + c0 + oc * 8);
#pragma unroll
      for (int j = 0; j < 8; ++j) {
        float f = ((float)v[j] - mq[j]) * rq[j];
        v[j] = (_Float16)(f > 0.f ? f : 0.f);
      }
      *(halfx8*)(&sX[p * 40 + oc * 8]) = v;
    }
    __syncthreads();
    for (int tap = 0; tap < 49; ++tap) {
      const int ky = tap / 7, kx = tap % 7;
      halfx8 wb = *(const halfx8*)(wt + ((size_t)tap * 16 + ln) * 64 + c0 + g * 8);
#pragma unroll
      for (int rr = 0; rr < 4; ++rr) {
        int y = wave * 4 + rr;
        halfx8 a = *(const halfx8*)(&sX[((y + ky) * 22 + ln + kx) * 40 + g * 8]);
        acc[rr] = __builtin_amdgcn_mfma_f32_16x16x32_f16(a, wb, acc[rr], 0, 0, 0);
      }
    }
  }
  if (ln < 3) {
    float bs = bias[ln];
#pragma unroll
    for (int rr = 0; rr < 4; ++rr) {
      int oy = ty0 + wave * 4 + rr;
#pragma unroll
      for (int i = 0; i < 4; ++i) {
        int ox = tx0 + g * 4 + i;
        out[((size_t)(b * 3 + ln) * H + oy) * W + ox] = tanhf(acc[rr][i] + bs);
      }
    }
  }
}

// ---------------- masked pooling --------------------------------------------
__global__ __launch_bounds__(256) void pool_sum_kernel(
    const float* __restrict__ f, const int* __restrict__ inst,
    float* __restrict__ P)
{
  const int N = 512 * 512;
  const int b = blockIdx.x, chunk = blockIdx.y;
  const int per = N / 32;
  const int base = chunk * per;
  float s0 = 0.f, s1 = 0.f, s2 = 0.f, c = 0.f;
  for (int i = base + threadIdx.x; i < base + per; i += 256) {
    if (inst[b * N + i] == 1) {
      c += 1.f;
      s0 += f[(size_t)(b * 3 + 0) * N + i];
      s1 += f[(size_t)(b * 3 + 1) * N + i];
      s2 += f[(size_t)(b * 3 + 2) * N + i];
    }
  }
#pragma unroll
  for (int off = 32; off > 0; off >>= 1) {
    s0 += __shfl_down(s0, off); s1 += __shfl_down(s1, off);
    s2 += __shfl_down(s2, off); c += __shfl_down(c, off);
  }
  __shared__ float red[4][4];
  int wv = threadIdx.x >> 6;
  if ((threadIdx.x & 63) == 0) {
    red[wv][0] = s0; red[wv][1] = s1; red[wv][2] = s2; red[wv][3] = c;
  }
  __syncthreads();
  if (threadIdx.x == 0) {
    float t0 = red[0][0] + red[1][0] + red[2][0] + red[3][0];
    float t1 = red[0][1] + red[1][1] + red[2][1] + red[3][1];
    float t2 = red[0][2] + red[1][2] + red[2][2] + red[3][2];
    float tc = red[0][3] + red[1][3] + red[2][3] + red[3][3];
    atomicAdd(&P[b * 4 + 0], t0);
    atomicAdd(&P[b * 4 + 1], t1);
    atomicAdd(&P[b * 4 + 2], t2);
    atomicAdd(&P[b * 4 + 3], tc);
  }
}

__global__ __launch_bounds__(256) void pool_scatter_kernel(
    const int* __restrict__ inst, const float* __restrict__ P,
    float* __restrict__ out)
{
  const int N = 512 * 512;
  int idx = blockIdx.x * 256 + threadIdx.x;
  if (idx >= 4 * N) return;
  int b = idx >> 18;
  int i = idx & (N - 1);
  bool m = inst[idx] == 1;
  float inv = 1.f / P[b * 4 + 3];
  out[(size_t)(b * 3 + 0) * N + i] = m ? P[b * 4 + 0] * inv : 0.f;
  out[(size_t)(b * 3 + 1) * N + i] = m ? P[b * 4 + 1] * inv : 0.f;
  out[(size_t)(b * 3 + 2) * N + i] = m ? P[b * 4 + 2] * inv : 0.f;
}

// ---------------------------------------------------------------------------
extern "C" void kernel_launch(void* const* d_in, const int* in_sizes, int n_in,
                              void* d_out, int out_size, void* d_ws, size_t ws_size,
                              hipStream_t stream)
{
  (void)in_sizes; (void)n_in; (void)out_size; (void)ws_size;
  const float* x    = (const float*)d_in[0];
  const int*   inst = (const int*)d_in[1];
  const float* w0   = (const float*)d_in[2];
  const float* b0   = (const float*)d_in[3];
  const float *dw[4], *db[4], *uw[4], *ub[4];
  for (int i = 0; i < 4; ++i) {
    dw[i] = (const float*)d_in[4 + 2 * i];
    db[i] = (const float*)d_in[5 + 2 * i];
    uw[i] = (const float*)d_in[12 + 2 * i];
    ub[i] = (const float*)d_in[13 + 2 * i];
  }
  const float* wf = (const float*)d_in[20];
  const float* bf = (const float*)d_in[21];

  // ---- workspace layout ----
  // A: [0, 134217728) half | B: [134217728, 201326592) half (F fp32 aliases B)
  // SS: 23552 floats (per-layer sum/sumsq slots) | P | weight scratch
  char* base = (char*)d_ws;
  half_t* A  = (half_t*)base;
  half_t* Bh = (half_t*)(base + 134217728);
  float*  F  = (float*)(base + 134217728);
  float*  SS = (float*)(base + 201326592);
  float*  P    = (float*)(base + 201326592 + 94208);
  half_t* WTp0 = (half_t*)(base + 201326592 + 95232);
  half_t* WTp1 = (half_t*)(base + 201326592 + 95232 + 147456);
  half_t* WTf  = (half_t*)(base + 201326592 + 95232 + 294912);
  half_t* WT0  = (half_t*)(base + 201326592 + 95232 + 294912 + 100352);
  half_t* WTA  = (half_t*)(base + 124780544);   // A-tail (dead-region reuse)
  half_t* WTB  = (half_t*)(base + 191889408);   // B-tail

  // stats slots (floats): S0..S8 for conv0,d0..d3,u0..u3 outputs
  float* S0 = SS;          float* S1 = SS + 512;   float* S2 = SS + 1536;
  float* S3 = SS + 3584;   float* S4 = SS + 7680;  float* S5 = SS + 15872;
  float* S6 = SS + 19968;  float* S7 = SS + 22016; float* S8 = SS + 23040;
  const float i512 = 1.f / (512.f * 512.f), i256 = 1.f / (256.f * 256.f),
              i128 = 1.f / (128.f * 128.f), i64 = 1.f / (64.f * 64.f),
              i32 = 1.f / (32.f * 32.f);

  auto XFORM = [&](const float* src, half_t* dst, int Ci, int Co, int mode) {
    int tot = Ci * Co * 9;
    transform_w<<<dim3((tot + 255) / 256), 256, 0, stream>>>(src, dst, Ci, Co, mode);
  };

  hipMemsetAsync(SS, 0, 94208 + 1024, stream);   // all stats slots + P

  // conv0 (MFMA, stats->S0) -> A
  transform_w0<<<dim3((7 * 64 * 32 + 255) / 256), 256, 0, stream>>>(w0, WT0);
  transform_wf<<<dim3((49 * 16 * 64 + 255) / 256), 256, 0, stream>>>(wf, WTf);
  conv0_mfma<<<dim3(1024, 4), 256, 0, stream>>>(x, WT0, b0, A, S0);

  // d0: A(64,512) -> B(128,256)
  XFORM(dw[0], WTp0, 64, 128, 0);
  down_mfma<<<dim3(1, 1024, 4), 256, 0, stream>>>(A, WTp0, db[0], S0, i512, Bh, S1, 64, 128, 512, 512);
  // d1: B -> A(256,128)
  XFORM(dw[1], WTA, 128, 256, 0);
  down_mfma<<<dim3(2, 256, 4), 256, 0, stream>>>(Bh, WTA, db[1], S1, i256, A, S2, 128, 256, 256, 256);
  // d2: A -> B(512,64)
  XFORM(dw[2], WTB, 256, 512, 0);
  down_mfma<<<dim3(4, 64, 4), 256, 0, stream>>>(A, WTB, db[2], S2, i128, Bh, S3, 256, 512, 128, 128);
  // d3: B -> A(1024,32)
  XFORM(dw[3], WTA, 512, 1024, 0);
  down_mfma<<<dim3(8, 16, 4), 256, 0, stream>>>(Bh, WTA, db[3], S3, i64, A, S4, 512, 1024, 64, 64);

  // u0: A(1024,32) -> B(512,64)
  XFORM(uw[0], WTB, 1024, 512, 1);
  up_mfma<<<dim3(8, 16, 4), 256, 0, stream>>>(A, WTB, ub[0], S4, i32, Bh, S5, 1024, 512, 32, 32);
  // u1: B -> A(256,128)
  XFORM(uw[1], WTA, 512, 256, 1);
  up_mfma<<<dim3(4, 64, 4), 256, 0, stream>>>(Bh, WTA, ub[1], S5, i64, A, S6, 512, 256, 64, 64);
  // u2: A -> B(128,256)
  XFORM(uw[2], WTA, 256, 128, 1);
  up_mfma<<<dim3(2, 256, 4), 256, 0, stream>>>(A, WTA, ub[2], S6, i128, Bh, S7, 256, 128, 128, 128);
  // u3: B -> A(64,512)
  XFORM(uw[3], WTp1, 128, 64, 1);
  up_mfma<<<dim3(1, 1024, 4), 256, 0, stream>>>(Bh, WTp1, ub[3], S7, i256, A, S8, 128, 64, 256, 256);

  // final conv (MFMA) -> F (fp32 CHW), then pooling
  convf_mfma<<<dim3(1024, 4), 256, 0, stream>>>(A, WTf, bf, S8, i512, F);
  pool_sum_kernel<<<dim3(4, 32), 256, 0, stream>>>(F, inst, P);
  pool_scatter_kernel<<<dim3(4096), 256, 0, stream>>>(inst, P, (float*)d_out);
}

// Round 8
// 1593.498 us; speedup vs baseline: 1.3046x; 1.3046x over previous
//
#include <hip/hip_runtime.h>
#include <math.h>

// ---------------------------------------------------------------------------
// Encoder on MI355X.
// NHWC fp16 activations; ALL convs as tap-wise implicit GEMM on
// mfma_f32_16x16x32_f16 (fp32 accum). InstanceNorm stats fused into each
// conv's epilogue via 32-way slot-spread atomicAdd partials (no contention);
// a tiny per-layer finalize kernel reduces slots -> mean/rstd and re-zeroes
// the slot buffer. Norm+ReLU fused into the next conv's staging.
// ---------------------------------------------------------------------------

typedef _Float16 half_t;
typedef _Float16 halfx8 __attribute__((ext_vector_type(8)));
typedef _Float16 halfx4 __attribute__((ext_vector_type(4)));
typedef float floatx4 __attribute__((ext_vector_type(4)));

#define NSLOT 32

// ---------------- weight transform: -> fp16 [tap][Cout][Cin] ----------------
// mode 0: src OIHW [Cout][Cin][3][3]; mode 1: src IOHW [Cin][Cout][3][3]
__global__ __launch_bounds__(256) void transform_w(
    const float* __restrict__ src, half_t* __restrict__ dst,
    int Cin, int Cout, int mode)
{
  int idx = blockIdx.x * 256 + threadIdx.x;
  int total = Cin * Cout * 9;
  if (idx >= total) return;
  int tap = idx % 9, t2 = idx / 9;
  int co, ci;
  if (mode == 0) { ci = t2 % Cin; co = t2 / Cin; }
  else           { co = t2 % Cout; ci = t2 / Cout; }
  dst[((size_t)tap * Cout + co) * Cin + ci] = (half_t)src[idx];
}

// final-conv weights: src [3][64][7][7] -> dst [tap49][co16(pad0)][ci64]
__global__ __launch_bounds__(256) void transform_wf(
    const float* __restrict__ src, half_t* __restrict__ dst)
{
  int idx = blockIdx.x * 256 + threadIdx.x;
  if (idx >= 49 * 16 * 64) return;
  int ci = idx & 63, t = idx >> 6;
  int co = t & 15, tap = t >> 4;
  float v = (co < 3) ? src[((size_t)co * 64 + ci) * 49 + tap] : 0.f;
  dst[idx] = (half_t)v;
}

// first-conv weights: src [64][3][7][7] -> dst [ky7][co64][k32], k=kx*4+ci
__global__ __launch_bounds__(256) void transform_w0(
    const float* __restrict__ src, half_t* __restrict__ dst)
{
  int idx = blockIdx.x * 256 + threadIdx.x;
  if (idx >= 7 * 64 * 32) return;
  int k = idx & 31, t = idx >> 5;
  int co = t & 63, ky = t >> 6;
  int kx = k >> 2, ci = k & 3;
  float v = (ci < 3 && kx < 7) ? src[(((size_t)co * 3 + ci) * 7 + ky) * 7 + kx] : 0.f;
  dst[idx] = (half_t)v;
}

// ---------------- finalize: reduce 32 slots -> mean/rstd, zero slots --------
__global__ __launch_bounds__(256) void finalize_stats(
    float* __restrict__ SSpart, float* __restrict__ mean,
    float* __restrict__ rstd, int total, float invN)
{
  int ch = blockIdx.x * 256 + threadIdx.x;
  if (ch >= total) return;
  float s = 0.f, s2 = 0.f;
#pragma unroll 4
  for (int k = 0; k < NSLOT; ++k) {
    s += SSpart[((size_t)ch * NSLOT + k) * 2];
    s2 += SSpart[((size_t)ch * NSLOT + k) * 2 + 1];
    SSpart[((size_t)ch * NSLOT + k) * 2] = 0.f;
    SSpart[((size_t)ch * NSLOT + k) * 2 + 1] = 0.f;
  }
  float m = s * invN;
  mean[ch] = m;
  rstd[ch] = rsqrtf(s2 * invN - m * m + 1e-5f);
}

// ---------------- conv0: reflect pad 3, 7x7, 3 -> 64, MFMA, stats-fused -----
__global__ __launch_bounds__(256) void conv0_mfma(
    const float* __restrict__ x, const half_t* __restrict__ wt,
    const float* __restrict__ bias, half_t* __restrict__ out,
    float* __restrict__ ssOut)
{
  const int H = 512, W = 512;
  __shared__ _Float16 sX[22 * 24 * 4];   // [row 22][col 24][ci 4]  (4.2 KB)
  __shared__ _Float16 sO[256 * 72];      // [pixel 256][co 64 pad 72] (36.9 KB)
  const int tile = blockIdx.x, b = blockIdx.y;
  const int tx0 = (tile & 31) << 4, ty0 = (tile >> 5) << 4;
  const int tid = threadIdx.x;
  const int wave = tid >> 6, lane = tid & 63;
  const int ln = lane & 15, g = lane >> 4;

  for (int u = tid; u < 22 * 24; u += 256) {
    int row = u / 24, col = u % 24;
    halfx4 v = {0, 0, 0, 0};
    if (col < 22) {
      int gy = ty0 + row - 3, gx = tx0 + col - 3;
      gy = gy < 0 ? -gy : (gy >= H ? 2 * H - 2 - gy : gy);
      gx = gx < 0 ? -gx : (gx >= W ? 2 * W - 2 - gx : gx);
      size_t p = (size_t)b * 3 * H * W + (size_t)gy * W + gx;
      v[0] = (_Float16)x[p];
      v[1] = (_Float16)x[p + H * W];
      v[2] = (_Float16)x[p + 2 * H * W];
    }
    *(halfx4*)(&sX[u * 4]) = v;
  }
  __syncthreads();

  floatx4 acc[4][4];
#pragma unroll
  for (int r = 0; r < 4; ++r)
#pragma unroll
    for (int n = 0; n < 4; ++n) acc[r][n] = floatx4{0.f, 0.f, 0.f, 0.f};

#pragma unroll
  for (int ky = 0; ky < 7; ++ky) {
    halfx8 wb[4];
#pragma unroll
    for (int nt = 0; nt < 4; ++nt)
      wb[nt] = *(const halfx8*)(wt + ((size_t)ky * 64 + nt * 16 + ln) * 32 + g * 8);
#pragma unroll
    for (int rr = 0; rr < 4; ++rr) {
      int y = wave * 4 + rr;
      halfx8 a = *(const halfx8*)(&sX[((y + ky) * 24 + ln + 2 * g) * 4]);
#pragma unroll
      for (int nt = 0; nt < 4; ++nt)
        acc[rr][nt] = __builtin_amdgcn_mfma_f32_16x16x32_f16(a, wb[nt], acc[rr][nt], 0, 0, 0);
    }
  }

  const int slot = (tile * 4 + wave) & (NSLOT - 1);
#pragma unroll
  for (int nt = 0; nt < 4; ++nt) {
    float bs = bias[nt * 16 + ln];
    float s = 0.f, s2 = 0.f;
#pragma unroll
    for (int rr = 0; rr < 4; ++rr)
#pragma unroll
      for (int i = 0; i < 4; ++i) {
        int p = (wave * 4 + rr) * 16 + g * 4 + i;
        float v = acc[rr][nt][i] + bs;
        s += v; s2 += v * v;
        sO[p * 72 + nt * 16 + ln] = (half_t)v;
      }
    s += __shfl_xor(s, 16); s += __shfl_xor(s, 32);
    s2 += __shfl_xor(s2, 16); s2 += __shfl_xor(s2, 32);
    if (g == 0) {
      size_t ch = (size_t)(b * 64 + nt * 16 + ln);
      atomicAdd(&ssOut[(ch * NSLOT + slot) * 2], s);
      atomicAdd(&ssOut[(ch * NSLOT + slot) * 2 + 1], s2);
    }
  }
  __syncthreads();
  {
    int p = tid;
    int oy = ty0 + (p >> 4), ox = tx0 + (p & 15);
    size_t ob = ((size_t)(b * 512 + oy) * 512 + ox) * 64;
#pragma unroll
    for (int j = 0; j < 8; ++j)
      *(halfx8*)(&out[ob + j * 8]) = *(const halfx8*)(&sO[p * 72 + j * 8]);
  }
}

// ---------------- down: 3x3 s2 conv, MFMA, norm-in + stats-out fused --------
__global__ __launch_bounds__(256) void down_mfma(
    const half_t* __restrict__ in, const half_t* __restrict__ wt,
    const float* __restrict__ bias, const float* __restrict__ mean,
    const float* __restrict__ rstd, half_t* __restrict__ out,
    float* __restrict__ ssOut, int Cin, int Cout, int IH, int IW)
{
  const int OH = IH >> 1, OW = IW >> 1;
  __shared__ _Float16 sX[9 * 33 * 40];  // [y 9][x 33][ci 32 pad 40]
  const int tid = threadIdx.x;
  const int wave = tid >> 6, lane = tid & 63;
  const int ln = lane & 15, g = lane >> 4;
  const int cog = blockIdx.x, b = blockIdx.z;
  const int ntx = OW >> 4;
  const int ox0 = (blockIdx.y % ntx) << 4, oy0 = (blockIdx.y / ntx) << 2;
  const int iy0 = 2 * oy0 - 1, ix0 = 2 * ox0 - 1;
  const int coW = cog * 128 + wave * 32;
  const int q = tid & 3;

  floatx4 acc[4][2];
#pragma unroll
  for (int r = 0; r < 4; ++r)
#pragma unroll
    for (int n = 0; n < 2; ++n) acc[r][n] = floatx4{0.f, 0.f, 0.f, 0.f};

  for (int c0 = 0; c0 < Cin; c0 += 32) {
    float mq[8], rq[8];
#pragma unroll
    for (int j = 0; j < 8; ++j) {
      int cc = c0 + q * 8 + j;
      mq[j] = mean[b * Cin + cc];
      rq[j] = rstd[b * Cin + cc];
    }
    __syncthreads();
    for (int idx = tid; idx < 9 * 33 * 4; idx += 256) {
      int p = idx >> 2;
      int y = p / 33, xx = p % 33;
      int gy = iy0 + y, gx = ix0 + xx;
      halfx8 v = {0, 0, 0, 0, 0, 0, 0, 0};
      if ((unsigned)gy < (unsigned)IH && (unsigned)gx < (unsigned)IW) {
        v = *(const halfx8*)(in + ((size_t)(b * IH + gy) * IW + gx) * Cin + c0 + q * 8);
#pragma unroll
        for (int j = 0; j < 8; ++j) {
          float f = ((float)v[j] - mq[j]) * rq[j];
          v[j] = (_Float16)(f > 0.f ? f : 0.f);
        }
      }
      *(halfx8*)(&sX[(y * 33 + xx) * 40 + q * 8]) = v;
    }
    __syncthreads();
#pragma unroll
    for (int tap = 0; tap < 9; ++tap) {
      const int ky = tap / 3, kx = tap % 3;
      halfx8 wb0 = *(const halfx8*)(wt + ((size_t)tap * Cout + coW + ln) * Cin + c0 + g * 8);
      halfx8 wb1 = *(const halfx8*)(wt + ((size_t)tap * Cout + coW + 16 + ln) * Cin + c0 + g * 8);
#pragma unroll
      for (int r = 0; r < 4; ++r) {
        halfx8 a = *(const halfx8*)(&sX[((2 * r + ky) * 33 + 2 * ln + kx) * 40 + g * 8]);
        acc[r][0] = __builtin_amdgcn_mfma_f32_16x16x32_f16(a, wb0, acc[r][0], 0, 0, 0);
        acc[r][1] = __builtin_amdgcn_mfma_f32_16x16x32_f16(a, wb1, acc[r][1], 0, 0, 0);
      }
    }
  }
  const int slot = blockIdx.y & (NSLOT - 1);
#pragma unroll
  for (int nt = 0; nt < 2; ++nt) {
    int co = coW + nt * 16 + ln;
    float bs = bias[co];
    float s = 0.f, s2 = 0.f;
#pragma unroll
    for (int r = 0; r < 4; ++r)
#pragma unroll
      for (int i = 0; i < 4; ++i) {
        int oy = oy0 + r, ox = ox0 + g * 4 + i;
        float v = acc[r][nt][i] + bs;
        s += v; s2 += v * v;
        out[((size_t)(b * OH + oy) * OW + ox) * Cout + co] = (half_t)v;
      }
    s += __shfl_xor(s, 16); s += __shfl_xor(s, 32);
    s2 += __shfl_xor(s2, 16); s2 += __shfl_xor(s2, 32);
    if (g == 0) {
      size_t ch = (size_t)(b * Cout + co);
      atomicAdd(&ssOut[(ch * NSLOT + slot) * 2], s);
      atomicAdd(&ssOut[(ch * NSLOT + slot) * 2 + 1], s2);
    }
  }
}

// ---------------- up: convT k3 s2, MFMA parity classes, fused stats ---------
__global__ __launch_bounds__(256) void up_mfma(
    const half_t* __restrict__ in, const half_t* __restrict__ wt,
    const float* __restrict__ bias, const float* __restrict__ mean,
    const float* __restrict__ rstd, half_t* __restrict__ out,
    float* __restrict__ ssOut, int Cin, int Cout, int IH, int IW)
{
  const int OH = IH << 1, OW = IW << 1;
  __shared__ _Float16 sX[5 * 17 * 40];  // [y 5][x 17][ci 32 pad 40]
  const int tid = threadIdx.x;
  const int wave = tid >> 6, lane = tid & 63;
  const int ln = lane & 15, g = lane >> 4;
  const int cog = blockIdx.x, b = blockIdx.z;
  const int ntx = OW >> 5;
  const int ox0 = (blockIdx.y % ntx) << 5, oy0 = (blockIdx.y / ntx) << 3;
  const int iyb = oy0 >> 1, ixb = ox0 >> 1;
  const int co = cog * 64 + wave * 16 + ln;
  const int q = tid & 3;

  floatx4 acc[4][4];  // [class][oyc]
#pragma unroll
  for (int c = 0; c < 4; ++c)
#pragma unroll
    for (int r = 0; r < 4; ++r) acc[c][r] = floatx4{0.f, 0.f, 0.f, 0.f};

  for (int c0 = 0; c0 < Cin; c0 += 32) {
    float mq[8], rq[8];
#pragma unroll
    for (int j = 0; j < 8; ++j) {
      int cc = c0 + q * 8 + j;
      mq[j] = mean[b * Cin + cc];
      rq[j] = rstd[b * Cin + cc];
    }
    __syncthreads();
    for (int idx = tid; idx < 5 * 17 * 4; idx += 256) {
      int p = idx >> 2;
      int y = p / 17, xx = p % 17;
      int gy = iyb + y, gx = ixb + xx;
      halfx8 v = {0, 0, 0, 0, 0, 0, 0, 0};
      if (gy < IH && gx < IW) {
        v = *(const halfx8*)(in + ((size_t)(b * IH + gy) * IW + gx) * Cin + c0 + q * 8);
#pragma unroll
        for (int j = 0; j < 8; ++j) {
          float f = ((float)v[j] - mq[j]) * rq[j];
          v[j] = (_Float16)(f > 0.f ? f : 0.f);
        }
      }
      *(halfx8*)(&sX[(y * 17 + xx) * 40 + q * 8]) = v;
    }
    __syncthreads();
#pragma unroll
    for (int tap = 0; tap < 9; ++tap) {
      const int ky = tap / 3, kx = tap % 3;
      const int cls = ((ky == 1) ? 0 : 2) + ((kx == 1) ? 0 : 1);
      const int dy = (ky == 0) ? 1 : 0;
      const int dx = (kx == 0) ? 1 : 0;
      halfx8 wb = *(const halfx8*)(wt + ((size_t)tap * Cout + co) * Cin + c0 + g * 8);
#pragma unroll
      for (int r = 0; r < 4; ++r) {
        halfx8 a = *(const halfx8*)(&sX[((r + dy) * 17 + ln + dx) * 40 + g * 8]);
        acc[cls][r] = __builtin_amdgcn_mfma_f32_16x16x32_f16(a, wb, acc[cls][r], 0, 0, 0);
      }
    }
  }
  float bs = bias[co];
  float s = 0.f, s2 = 0.f;
#pragma unroll
  for (int cls = 0; cls < 4; ++cls) {
    const int ey = cls >> 1, ex = cls & 1;
#pragma unroll
    for (int r = 0; r < 4; ++r)
#pragma unroll
      for (int i = 0; i < 4; ++i) {
        int oy = oy0 + 2 * r + ey;
        int ox = ox0 + 2 * (g * 4 + i) + ex;
        float v = acc[cls][r][i] + bs;
        s += v; s2 += v * v;
        out[((size_t)(b * OH + oy) * OW + ox) * Cout + co] = (half_t)v;
      }
  }
  s += __shfl_xor(s, 16); s += __shfl_xor(s, 32);
  s2 += __shfl_xor(s2, 16); s2 += __shfl_xor(s2, 32);
  if (g == 0) {
    const int slot = blockIdx.y & (NSLOT - 1);
    size_t ch = (size_t)(b * Cout + co);
    atomicAdd(&ssOut[(ch * NSLOT + slot) * 2], s);
    atomicAdd(&ssOut[(ch * NSLOT + slot) * 2 + 1], s2);
  }
}

// ---------------- final: reflect pad 3, 7x7, 64 -> 3, MFMA + tanh -----------
// ci-chunked staging (32 at a time) -> 38.7 KB LDS -> 4 blocks/CU.
__global__ __launch_bounds__(256) void convf_mfma(
    const half_t* __restrict__ in, const half_t* __restrict__ wt,
    const float* __restrict__ bias, const float* __restrict__ mean,
    const float* __restrict__ rstd, float* __restrict__ out)
{
  const int H = 512, W = 512;
  __shared__ _Float16 sX[484 * 40];   // [pixel 484][ci 32 pad 40] = 38.7 KB
  const int tile = blockIdx.x, b = blockIdx.y;
  const int tx0 = (tile & 31) << 4, ty0 = (tile >> 5) << 4;
  const int tid = threadIdx.x;
  const int wave = tid >> 6, lane = tid & 63;
  const int ln = lane & 15, g = lane >> 4;
  const int oc = tid & 3;

  floatx4 acc[4];
#pragma unroll
  for (int r = 0; r < 4; ++r) acc[r] = floatx4{0.f, 0.f, 0.f, 0.f};

  for (int c0 = 0; c0 < 64; c0 += 32) {
    float mq[8], rq[8];
#pragma unroll
    for (int j = 0; j < 8; ++j) {
      int cc = c0 + oc * 8 + j;
      mq[j] = mean[b * 64 + cc];
      rq[j] = rstd[b * 64 + cc];
    }
    __syncthreads();
    for (int u = tid; u < 484 * 4; u += 256) {
      int p = u >> 2;
      int iy = p / 22, ix = p % 22;
      int gy = ty0 + iy - 3, gx = tx0 + ix - 3;
      gy = gy < 0 ? -gy : (gy >= H ? 2 * H - 2 - gy : gy);
      gx = gx < 0 ? -gx : (gx >= W ? 2 * W - 2 - gx : gx);
      halfx8 v = *(const halfx8*)(in + ((size_t)(b * H + gy) * W + gx) * 64 + c0 + oc * 8);
#pragma unroll
      for (int j = 0; j < 8; ++j) {
        float f = ((float)v[j] - mq[j]) * rq[j];
        v[j] = (_Float16)(f > 0.f ? f : 0.f);
      }
      *(halfx8*)(&sX[p * 40 + oc * 8]) = v;
    }
    __syncthreads();
    for (int tap = 0; tap < 49; ++tap) {
      const int ky = tap / 7, kx = tap % 7;
      halfx8 wb = *(const halfx8*)(wt + ((size_t)tap * 16 + ln) * 64 + c0 + g * 8);
#pragma unroll
      for (int rr = 0; rr < 4; ++rr) {
        int y = wave * 4 + rr;
        halfx8 a = *(const halfx8*)(&sX[((y + ky) * 22 + ln + kx) * 40 + g * 8]);
        acc[rr] = __builtin_amdgcn_mfma_f32_16x16x32_f16(a, wb, acc[rr], 0, 0, 0);
      }
    }
  }
  if (ln < 3) {
    float bs = bias[ln];
#pragma unroll
    for (int rr = 0; rr < 4; ++rr) {
      int oy = ty0 + wave * 4 + rr;
#pragma unroll
      for (int i = 0; i < 4; ++i) {
        int ox = tx0 + g * 4 + i;
        out[((size_t)(b * 3 + ln) * H + oy) * W + ox] = tanhf(acc[rr][i] + bs);
      }
    }
  }
}

// ---------------- masked pooling --------------------------------------------
__global__ __launch_bounds__(256) void pool_sum_kernel(
    const float* __restrict__ f, const int* __restrict__ inst,
    float* __restrict__ P)
{
  const int N = 512 * 512;
  const int b = blockIdx.x, chunk = blockIdx.y;
  const int per = N / 32;
  const int base = chunk * per;
  float s0 = 0.f, s1 = 0.f, s2 = 0.f, c = 0.f;
  for (int i = base + threadIdx.x; i < base + per; i += 256) {
    if (inst[b * N + i] == 1) {
      c += 1.f;
      s0 += f[(size_t)(b * 3 + 0) * N + i];
      s1 += f[(size_t)(b * 3 + 1) * N + i];
      s2 += f[(size_t)(b * 3 + 2) * N + i];
    }
  }
#pragma unroll
  for (int off = 32; off > 0; off >>= 1) {
    s0 += __shfl_down(s0, off); s1 += __shfl_down(s1, off);
    s2 += __shfl_down(s2, off); c += __shfl_down(c, off);
  }
  __shared__ float red[4][4];
  int wv = threadIdx.x >> 6;
  if ((threadIdx.x & 63) == 0) {
    red[wv][0] = s0; red[wv][1] = s1; red[wv][2] = s2; red[wv][3] = c;
  }
  __syncthreads();
  if (threadIdx.x == 0) {
    float t0 = red[0][0] + red[1][0] + red[2][0] + red[3][0];
    float t1 = red[0][1] + red[1][1] + red[2][1] + red[3][1];
    float t2 = red[0][2] + red[1][2] + red[2][2] + red[3][2];
    float tc = red[0][3] + red[1][3] + red[2][3] + red[3][3];
    atomicAdd(&P[b * 4 + 0], t0);
    atomicAdd(&P[b * 4 + 1], t1);
    atomicAdd(&P[b * 4 + 2], t2);
    atomicAdd(&P[b * 4 + 3], tc);
  }
}

__global__ __launch_bounds__(256) void pool_scatter_kernel(
    const int* __restrict__ inst, const float* __restrict__ P,
    float* __restrict__ out)
{
  const int N = 512 * 512;
  int idx = blockIdx.x * 256 + threadIdx.x;
  if (idx >= 4 * N) return;
  int b = idx >> 18;
  int i = idx & (N - 1);
  bool m = inst[idx] == 1;
  float inv = 1.f / P[b * 4 + 3];
  out[(size_t)(b * 3 + 0) * N + i] = m ? P[b * 4 + 0] * inv : 0.f;
  out[(size_t)(b * 3 + 1) * N + i] = m ? P[b * 4 + 1] * inv : 0.f;
  out[(size_t)(b * 3 + 2) * N + i] = m ? P[b * 4 + 2] * inv : 0.f;
}

// ---------------------------------------------------------------------------
extern "C" void kernel_launch(void* const* d_in, const int* in_sizes, int n_in,
                              void* d_out, int out_size, void* d_ws, size_t ws_size,
                              hipStream_t stream)
{
  (void)in_sizes; (void)n_in; (void)out_size; (void)ws_size;
  const float* x    = (const float*)d_in[0];
  const int*   inst = (const int*)d_in[1];
  const float* w0   = (const float*)d_in[2];
  const float* b0   = (const float*)d_in[3];
  const float *dw[4], *db[4], *uw[4], *ub[4];
  for (int i = 0; i < 4; ++i) {
    dw[i] = (const float*)d_in[4 + 2 * i];
    db[i] = (const float*)d_in[5 + 2 * i];
    uw[i] = (const float*)d_in[12 + 2 * i];
    ub[i] = (const float*)d_in[13 + 2 * i];
  }
  const float* wf = (const float*)d_in[20];
  const float* bf = (const float*)d_in[21];

  // ---- workspace layout ----
  // A: [0, 134217728) half | B: [134217728, 201326592) half (F fp32 aliases B)
  // SSpart: 1 MB slot-spread partials (reused every layer, self-zeroing)
  // P | mean | rstd | weight scratch
  char* base = (char*)d_ws;
  half_t* A  = (half_t*)base;
  half_t* Bh = (half_t*)(base + 134217728);
  float*  F  = (float*)(base + 134217728);
  float*  SSp   = (float*)(base + 201326592);                  // 1,048,576 B
  float*  P     = (float*)(base + 201326592 + 1048576);        // 1 KB
  float*  S_mean= (float*)(base + 201326592 + 1048576 + 1024); // 16 KB
  float*  S_rstd= (float*)(base + 201326592 + 1048576 + 17408);// 16 KB
  half_t* WTp0  = (half_t*)(base + 201326592 + 1048576 + 33792);
  half_t* WTp1  = (half_t*)(base + 201326592 + 1048576 + 33792 + 147456);
  half_t* WTf   = (half_t*)(base + 201326592 + 1048576 + 33792 + 294912);
  half_t* WT0   = (half_t*)(base + 201326592 + 1048576 + 33792 + 294912 + 100352);
  half_t* WTA   = (half_t*)(base + 124780544);   // A-tail (dead-region reuse)
  half_t* WTB   = (half_t*)(base + 191889408);   // B-tail

  const float i512 = 1.f / (512.f * 512.f), i256 = 1.f / (256.f * 256.f),
              i128 = 1.f / (128.f * 128.f), i64 = 1.f / (64.f * 64.f),
              i32 = 1.f / (32.f * 32.f);

  auto XFORM = [&](const float* src, half_t* dst, int Ci, int Co, int mode) {
    int tot = Ci * Co * 9;
    transform_w<<<dim3((tot + 255) / 256), 256, 0, stream>>>(src, dst, Ci, Co, mode);
  };
  auto FIN = [&](int C, float invN) {
    finalize_stats<<<dim3((4 * C + 255) / 256), 256, 0, stream>>>(
        SSp, S_mean, S_rstd, 4 * C, invN);
  };

  hipMemsetAsync(SSp, 0, 1048576 + 1024, stream);   // slot partials + P

  // conv0 (MFMA, stats->SSp) -> A
  transform_w0<<<dim3((7 * 64 * 32 + 255) / 256), 256, 0, stream>>>(w0, WT0);
  transform_wf<<<dim3((49 * 16 * 64 + 255) / 256), 256, 0, stream>>>(wf, WTf);
  conv0_mfma<<<dim3(1024, 4), 256, 0, stream>>>(x, WT0, b0, A, SSp);
  FIN(64, i512);

  // d0: A(64,512) -> B(128,256)
  XFORM(dw[0], WTp0, 64, 128, 0);
  down_mfma<<<dim3(1, 1024, 4), 256, 0, stream>>>(A, WTp0, db[0], S_mean, S_rstd, Bh, SSp, 64, 128, 512, 512);
  FIN(128, i256);
  // d1: B -> A(256,128)
  XFORM(dw[1], WTA, 128, 256, 0);
  down_mfma<<<dim3(2, 256, 4), 256, 0, stream>>>(Bh, WTA, db[1], S_mean, S_rstd, A, SSp, 128, 256, 256, 256);
  FIN(256, i128);
  // d2: A -> B(512,64)
  XFORM(dw[2], WTB, 256, 512, 0);
  down_mfma<<<dim3(4, 64, 4), 256, 0, stream>>>(A, WTB, db[2], S_mean, S_rstd, Bh, SSp, 256, 512, 128, 128);
  FIN(512, i64);
  // d3: B -> A(1024,32)
  XFORM(dw[3], WTA, 512, 1024, 0);
  down_mfma<<<dim3(8, 16, 4), 256, 0, stream>>>(Bh, WTA, db[3], S_mean, S_rstd, A, SSp, 512, 1024, 64, 64);
  FIN(1024, i32);

  // u0: A(1024,32) -> B(512,64)
  XFORM(uw[0], WTB, 1024, 512, 1);
  up_mfma<<<dim3(8, 16, 4), 256, 0, stream>>>(A, WTB, ub[0], S_mean, S_rstd, Bh, SSp, 1024, 512, 32, 32);
  FIN(512, i64);
  // u1: B -> A(256,128)
  XFORM(uw[1], WTA, 512, 256, 1);
  up_mfma<<<dim3(4, 64, 4), 256, 0, stream>>>(Bh, WTA, ub[1], S_mean, S_rstd, A, SSp, 512, 256, 64, 64);
  FIN(256, i128);
  // u2: A -> B(128,256)
  XFORM(uw[2], WTA, 256, 128, 1);
  up_mfma<<<dim3(2, 256, 4), 256, 0, stream>>>(A, WTA, ub[2], S_mean, S_rstd, Bh, SSp, 256, 128, 128, 128);
  FIN(128, i256);
  // u3: B -> A(64,512)
  XFORM(uw[3], WTp1, 128, 64, 1);
  up_mfma<<<dim3(1, 1024, 4), 256, 0, stream>>>(Bh, WTp1, ub[3], S_mean, S_rstd, A, SSp, 128, 64, 256, 256);
  FIN(64, i512);

  // final conv (MFMA) -> F (fp32 CHW), then pooling
  convf_mfma<<<dim3(1024, 4), 256, 0, stream>>>(A, WTf, bf, S_mean, S_rstd, F);
  pool_sum_kernel<<<dim3(4, 32), 256, 0, stream>>>(F, inst, P);
  pool_scatter_kernel<<<dim3(4096), 256, 0, stream>>>(inst, P, (float*)d_out);
}